// Round 1
// baseline (1430.140 us; speedup 1.0000x reference)
//
#include <hip/hip_runtime.h>
#include <cmath>

// Problem constants
#define BATCH 128
#define KCH 32
#define IMHW 80

// ---------------------------------------------------------------------------
// Block-wide reductions (256 threads = 4 waves of 64)
// ---------------------------------------------------------------------------
__device__ __forceinline__ float block_sum(float v, float* red) {
    for (int off = 32; off; off >>= 1) v += __shfl_xor(v, off);
    __syncthreads();
    if ((threadIdx.x & 63) == 0) red[threadIdx.x >> 6] = v;
    __syncthreads();
    return red[0] + red[1] + red[2] + red[3];
}

__device__ __forceinline__ float block_max(float v, float* red) {
    for (int off = 32; off; off >>= 1) v = fmaxf(v, __shfl_xor(v, off));
    __syncthreads();
    if ((threadIdx.x & 63) == 0) red[threadIdx.x >> 6] = v;
    __syncthreads();
    return fmaxf(fmaxf(red[0], red[1]), fmaxf(red[2], red[3]));
}

// ---------------------------------------------------------------------------
// 3x3 VALID conv, fp32. 16x16 output tile per block (256 threads).
// Thread layout: 4 channel-groups x 64 px threads (8x8), each thread computes
// 2x2 pixels at stride 8 (keeps LDS reads stride-1 -> <=2-way bank aliasing)
// for GC=(COUT+3)/4 output channels. Weights are wave-uniform scalar loads.
// ---------------------------------------------------------------------------
template<int CIN, int COUT, int INHW, int OUTHW, bool RELU, bool SUB33>
__global__ __launch_bounds__(256) void conv3x3_kernel(
    const float* __restrict__ in, const float* __restrict__ w,
    const float* __restrict__ bias, float* __restrict__ out)
{
    constexpr int NT  = (OUTHW + 15) / 16;   // tiles per dim (5 for 74/76/78)
    constexpr int ILD = 18;                   // input tile leading dim
    constexpr int ISZ = ILD * ILD;
    constexpr int GC  = (COUT + 3) / 4;       // out-channels per group

    __shared__ float ld_in[CIN * ISZ];

    const int tid = threadIdx.x;
    const int blk = blockIdx.x;
    const int b   = blk / (NT * NT);
    const int t   = blk % (NT * NT);
    const int ty0 = (t / NT) * 16, tx0 = (t % NT) * 16;

    const float* inb = in + (size_t)b * CIN * INHW * INHW;
    for (int i = tid; i < CIN * ISZ; i += 256) {
        int c  = i / ISZ, r = i % ISZ;
        int iy = r / ILD, ix = r % ILD;
        int gy = min(ty0 + iy, INHW - 1);
        int gx = min(tx0 + ix, INHW - 1);
        float v = inb[((size_t)c * INHW + gy) * INHW + gx];
        if (SUB33) v -= 0.33f;
        ld_in[i] = v;
    }
    __syncthreads();

    const int g  = __builtin_amdgcn_readfirstlane(tid >> 6);  // wave-uniform group
    const int p  = tid & 63;
    const int px = p & 7, py = p >> 3;
    const int oc0 = g * GC;

    float acc[GC][2][2];
#pragma unroll
    for (int q = 0; q < GC; q++)
        acc[q][0][0] = acc[q][0][1] = acc[q][1][0] = acc[q][1][1] = 0.f;

    for (int c = 0; c < CIN; c++) {
        const float* lin = ld_in + c * ISZ;
        float wreg[GC][9];
#pragma unroll
        for (int q = 0; q < GC; q++) {
            int oc = min(oc0 + q, COUT - 1);           // clamp (masked on write)
            const float* wp = w + ((size_t)oc * CIN + c) * 9;
#pragma unroll
            for (int kk = 0; kk < 9; kk++) wreg[q][kk] = wp[kk];
        }
#pragma unroll
        for (int ky = 0; ky < 3; ky++) {
#pragma unroll
            for (int kx = 0; kx < 3; kx++) {
                float v00 = lin[(py     + ky) * ILD + px     + kx];
                float v01 = lin[(py     + ky) * ILD + px + 8 + kx];
                float v10 = lin[(py + 8 + ky) * ILD + px     + kx];
                float v11 = lin[(py + 8 + ky) * ILD + px + 8 + kx];
#pragma unroll
                for (int q = 0; q < GC; q++) {
                    float wv = wreg[q][ky * 3 + kx];
                    acc[q][0][0] = fmaf(wv, v00, acc[q][0][0]);
                    acc[q][0][1] = fmaf(wv, v01, acc[q][0][1]);
                    acc[q][1][0] = fmaf(wv, v10, acc[q][1][0]);
                    acc[q][1][1] = fmaf(wv, v11, acc[q][1][1]);
                }
            }
        }
    }

    float* outb = out + (size_t)b * COUT * OUTHW * OUTHW;
#pragma unroll
    for (int q = 0; q < GC; q++) {
        int oc = oc0 + q;
        if (oc >= COUT) break;
        float bv = bias[oc];
#pragma unroll
        for (int yy = 0; yy < 2; yy++) {
            int y = ty0 + py + yy * 8;
            if (y >= OUTHW) continue;
#pragma unroll
            for (int xx = 0; xx < 2; xx++) {
                int x = tx0 + px + xx * 8;
                if (x >= OUTHW) continue;
                float v = acc[q][yy][xx] + bv;
                if (RELU) v = fmaxf(v, 0.f);
                outb[((size_t)oc * OUTHW + y) * OUTHW + x] = v;
            }
        }
    }
}

// ---------------------------------------------------------------------------
// Fused bilinear 74->80 upsample (half-pixel, clamped) + T=400 softmax over
// 6400 px + soft-argmax + optional map store + optional overlap(img_change).
// One block per (b,k). dense: [Bc,K,74,74]
// ---------------------------------------------------------------------------
__global__ __launch_bounds__(256) void softargmax_kernel(
    const float* __restrict__ dense,
    float* __restrict__ mapOut,        // [.,K,80,80] or null
    float* __restrict__ kpOut,         // [.,K,2]
    const float* __restrict__ chg,     // [.,80,80] or null
    float* __restrict__ overlapOut)    // [.,K] or null
{
    __shared__ float ld_d[74 * 74];
    __shared__ float ld_e[6400];
    __shared__ int   ld_i0[80];
    __shared__ int   ld_i1[80];
    __shared__ float ld_f[80];
    __shared__ float red[4];

    const int tid = threadIdx.x;
    const int bk  = blockIdx.x;
    const int bloc = bk >> 5;                  // local batch index

    const float* d = dense + (size_t)bk * 5476;
    for (int i = tid; i < 5476; i += 256) ld_d[i] = d[i];
    if (tid < 80) {
        float s  = ((float)tid + 0.5f) * (74.0f / 80.0f) - 0.5f;
        float fl = floorf(s);
        int   i0 = (int)fl;
        ld_i0[tid] = max(i0, 0);
        ld_i1[tid] = min(i0 + 1, 73);
        ld_f[tid]  = s - fl;
    }
    __syncthreads();

    // pass 1: logits -> ld_e, track max
    float lmax = -1e30f;
#pragma unroll
    for (int it = 0; it < 25; it++) {
        int p  = tid + it * 256;
        int oy = p / 80, ox = p % 80;
        int y0 = ld_i0[oy], y1 = ld_i1[oy];
        float fy = ld_f[oy];
        int x0 = ld_i0[ox], x1 = ld_i1[ox];
        float fx = ld_f[ox];
        const float* r0 = ld_d + y0 * 74;
        const float* r1 = ld_d + y1 * 74;
        float a0 = r0[x0], a1 = r0[x1], b0 = r1[x0], b1 = r1[x1];
        float v0 = a0 + fx * (a1 - a0);
        float v1 = b0 + fx * (b1 - b0);
        float v  = v0 + fy * (v1 - v0);
        float lg = 400.0f * v;
        ld_e[p] = lg;
        lmax = fmaxf(lmax, lg);
    }
    float M = block_max(lmax, red);

    // pass 2: exp, sums
    float s = 0.f, cx = 0.f, cy = 0.f, ov = 0.f;
    const float* chgb = chg ? (chg + (size_t)bloc * 6400) : nullptr;
#pragma unroll
    for (int it = 0; it < 25; it++) {
        int p = tid + it * 256;
        float e = __expf(ld_e[p] - M);
        ld_e[p] = e;
        s += e;
        int oy = p / 80, ox = p % 80;
        cx += e * (float)ox;
        cy += e * (float)oy;
        if (chgb) ov += e * chgb[p];
    }
    float S  = block_sum(s, red);
    float CX = block_sum(cx, red);
    float CY = block_sum(cy, red);
    float OV = chgb ? block_sum(ov, red) : 0.f;
    float inv = 1.0f / S;

    // pass 3: normalized map store
    if (mapOut) {
        float* mo = mapOut + (size_t)bk * 6400;
#pragma unroll
        for (int it = 0; it < 25; it++) {
            int p = tid + it * 256;
            mo[p] = ld_e[p] * inv;
        }
    }
    if (tid == 0) {
        kpOut[(size_t)bk * 2]     = CX * inv;   // col (x-weighted)
        kpOut[(size_t)bk * 2 + 1] = CY * inv;   // row (y-weighted)
        if (overlapOut) overlapOut[bk] = OV * inv;
    }
}

// ---------------------------------------------------------------------------
// img_change = (sum_c |first_prev - first| > 0), plus valid[b] flag
// ---------------------------------------------------------------------------
__global__ __launch_bounds__(256) void imgchange_kernel(
    const float* __restrict__ first, const float* __restrict__ first_prev,
    float* __restrict__ chgOut, float* __restrict__ validOut)
{
    __shared__ float red[4];
    const int b = blockIdx.x, tid = threadIdx.x;
    const float* f  = first      + (size_t)b * 3 * 6400;
    const float* fp = first_prev + (size_t)b * 3 * 6400;
    float cnt = 0.f;
#pragma unroll
    for (int it = 0; it < 25; it++) {
        int p = tid + it * 256;
        float s = fabsf(fp[p] - f[p])
                + fabsf(fp[p + 6400] - f[p + 6400])
                + fabsf(fp[p + 12800] - f[p + 12800]);
        float c = (s > 0.f) ? 1.f : 0.f;
        chgOut[(size_t)b * 6400 + p] = c;
        cnt += c;
    }
    float tot = block_sum(cnt, red);
    if (tid == 0) validOut[b] = (tot > 0.f) ? 1.f : 0.f;
}

// ---------------------------------------------------------------------------
// Final losses: [kcl, scl, kvl, ssl]
// ---------------------------------------------------------------------------
__global__ __launch_bounds__(256) void loss_kernel(
    const float* __restrict__ kp1, const float* __restrict__ kpp,
    const float* __restrict__ ov, const float* __restrict__ valid,
    float* __restrict__ lossOut)
{
    __shared__ float red[4];
    const int tid = threadIdx.x;

    // kcl
    float a = 0.f;
    for (int i = tid; i < BATCH * KCH; i += 256) {
        float dx = kp1[2 * i]     - kpp[2 * i];
        float dy = kp1[2 * i + 1] - kpp[2 * i + 1];
        a += dx * dx + dy * dy;
    }
    float kcl = block_sum(a, red) / (float)(BATCH * KCH);

    // nvalid
    a = (tid < BATCH) ? valid[tid] : 0.f;
    float nv = fmaxf(block_sum(a, red), 1.0f);

    // scl
    a = 0.f;
    for (int i = tid; i < BATCH * KCH; i += 256) {
        int b = i >> 5;
        a += valid[b] * (-logf(1e-7f + ov[i]));
    }
    float scl = block_sum(a, red) / (nv * (float)KCH);

    // ssl
    a = 0.f;
    if (tid < BATCH) {
        float so = 0.f;
        for (int k = 0; k < KCH; k++) so += ov[tid * KCH + k];
        a = valid[tid] * (-logf(1e-7f + so));
    }
    float ssl = block_sum(a, red) / nv;

    // kvl (faithful to the reference's j<2 loop)
    a = 0.f;
    for (int i = tid; i < BATCH * KCH; i += 256) {
        int b = i >> 5, kk = i & 31;
        float x = kp1[2 * i], y = kp1[2 * i + 1];
#pragma unroll
        for (int j = 0; j < 2; j++) {
            if (kk == j) continue;
            float xj = kp1[((size_t)b * KCH + j) * 2];
            float yj = kp1[((size_t)b * KCH + j) * 2 + 1];
            float dx = x - xj, dy = y - yj;
            float d2 = dx * dx + dy * dy;
            a += fmaxf(9.0f - d2, 0.0f);
        }
    }
    float kvl = block_sum(a, red) / (float)(KCH * KCH * BATCH);

    if (tid == 0) {
        lossOut[0] = kcl;
        lossOut[1] = scl;
        lossOut[2] = kvl;
        lossOut[3] = ssl;
    }
}

// ---------------------------------------------------------------------------
extern "C" void kernel_launch(void* const* d_in, const int* in_sizes, int n_in,
                              void* d_out, int out_size, void* d_ws, size_t ws_size,
                              hipStream_t stream)
{
    const float* first      = (const float*)d_in[0];
    const float* first_prev = (const float*)d_in[1];
    const float* second     = (const float*)d_in[2];
    const float* w1 = (const float*)d_in[3];
    const float* b1 = (const float*)d_in[4];
    const float* w2 = (const float*)d_in[5];
    const float* b2 = (const float*)d_in[6];
    const float* w3 = (const float*)d_in[7];
    const float* b3 = (const float*)d_in[8];
    float* out = (float*)d_out;
    float* ws  = (float*)d_ws;

    // output layout (floats)
    const size_t kp1Off  = 0;
    const size_t kp2Off  = (size_t)BATCH * KCH * 2;
    const size_t kppOff  = 2 * kp2Off;
    const size_t map1Off = 3 * kp2Off;
    const size_t mapSz   = (size_t)BATCH * KCH * IMHW * IMHW;
    const size_t map2Off = map1Off + mapSz;
    const size_t chgOff  = map2Off + mapSz;
    const size_t lossOff = chgOff + (size_t)BATCH * IMHW * IMHW;

    // workspace: [y2: Bc*30*76*76][shared y1/dense: Bc*32*74*74][overlap][valid]
    const size_t y2PerB = 30 * 76 * 76;          // 173280
    const size_t shPerB = 32 * 74 * 74;          // 175232 (>= 20*78*78)
    int Bc = BATCH;
    while (Bc > 1) {
        size_t need = ((size_t)Bc * (y2PerB + shPerB) + BATCH * KCH + BATCH) * 4;
        if (need <= ws_size) break;
        Bc >>= 1;
    }
    const int nchunk = BATCH / Bc;
    float* ws_y2 = ws;
    float* ws_sh = ws + (size_t)Bc * y2PerB;
    float* ws_ov = ws_sh + (size_t)Bc * shPerB;
    float* ws_va = ws_ov + (size_t)BATCH * KCH;

    imgchange_kernel<<<BATCH, 256, 0, stream>>>(first, first_prev, out + chgOff, ws_va);

    const float* xin[3] = { first, first_prev, second };
    for (int ch = 0; ch < nchunk; ch++) {
        const int b0 = ch * Bc;
        for (int s = 0; s < 3; s++) {
            const float* x = xin[s] + (size_t)b0 * 3 * IMHW * IMHW;
            conv3x3_kernel<3, 20, 80, 78, true,  true ><<<Bc * 25, 256, 0, stream>>>(x,     w1, b1, ws_sh);
            conv3x3_kernel<20, 30, 78, 76, true,  false><<<Bc * 25, 256, 0, stream>>>(ws_sh, w2, b2, ws_y2);
            conv3x3_kernel<30, 32, 76, 74, false, false><<<Bc * 25, 256, 0, stream>>>(ws_y2, w3, b3, ws_sh);

            float* mapOut = nullptr;
            float* kpOut  = nullptr;
            const float* chg = nullptr;
            float* ovOut  = nullptr;
            if (s == 0) {
                mapOut = out + map1Off + (size_t)b0 * KCH * IMHW * IMHW;
                kpOut  = out + kp1Off  + (size_t)b0 * KCH * 2;
                chg    = out + chgOff  + (size_t)b0 * IMHW * IMHW;
                ovOut  = ws_ov + (size_t)b0 * KCH;
            } else if (s == 1) {
                kpOut  = out + kppOff + (size_t)b0 * KCH * 2;
            } else {
                mapOut = out + map2Off + (size_t)b0 * KCH * IMHW * IMHW;
                kpOut  = out + kp2Off  + (size_t)b0 * KCH * 2;
            }
            softargmax_kernel<<<Bc * KCH, 256, 0, stream>>>(ws_sh, mapOut, kpOut, chg, ovOut);
        }
    }

    loss_kernel<<<1, 256, 0, stream>>>(out + kp1Off, out + kppOff, ws_ov, ws_va, out + lossOff);
}